// Round 11
// baseline (295.786 us; speedup 1.0000x reference)
//
#include <hip/hip_runtime.h>
#include <hip/hip_fp16.h>

// ---------------------------------------------------------------------------
// N=400000, E=2000000, B=8, C_IN=4, N_EDGE_TYPE=5, N_NODE_TYPE=7, C_OUT=32.
//
// HW model (measured, rounds 0-10):
//  - Global atomics into 88MB fp32 thrash L2 (R1); spread non-returning
//    atomics into L2-resident targets are fast (R1 ~300G/s).
//  - Write-merge RULE: regions >= ~64B or write-allocate amplification (R3).
//  - consume's 80us floor WAS the 10M LDS atomics (R10: removing them ->
//    58us, VALUBusy 13->79%). Now VALU-bound: 4x-redundant replica
//    accumulate + divergence (wave pays max-degree ~15, mean 5).
//  - repack: two 16MB passes + 196 blocks (0.77/CU).
//  => R11: (1) consume splits records across the 4 hf-replicas (+LDS
//     3-pass combine, staging-buffer reuse, stride-43 padding);
//     (2) node-level hist built in histW via 8 per-XCD global replicas ->
//     repack is single-pass; (3) scatter CH=2048 (4 blk/CU).
// ---------------------------------------------------------------------------

#define CH      2048       // edges per chunk
#define CW      2048       // coarse bucket width (nodes)
#define CWSH    11         // log2(CW)
#define WSZ     128        // consume window (nodes)
#define WSH     7          // log2(WSZ)
#define NBCMAX  512        // max coarse buckets
#define CAP     2048       // consume stage capacity (records)

__device__ __forceinline__ unsigned pack2(float a, float b) {
    __half2 h = __floats2half2_rn(a, b);
    union { __half2 h; unsigned u; } cv; cv.h = h; return cv.u;
}
__device__ __forceinline__ float2 unpack2(unsigned u) {
    union { unsigned u; __half2 h; } cv; cv.u = u;
    return __half22float2(cv.h);
}

// ---- histW: chunk blocks: coarse LDS hist + node-replica global hist +
// ---- x->fp16 slice (int4 loads). extra 8 blocks: temb stage1 -------------
__global__ __launch_bounds__(256) void histW_kernel(
    const int* __restrict__ ei, int* __restrict__ counts,
    int* __restrict__ nodeRep,
    const float* __restrict__ x, uint2* __restrict__ xh,
    const float* __restrict__ t, const float* __restrict__ W1,
    float* __restrict__ h1acc, float* __restrict__ h2acc,
    float* __restrict__ inj,
    int E, int N, int NBC, int NCHP)
{
    int tid = threadIdx.x;
    if ((int)blockIdx.x >= NCHP) {
        int b = blockIdx.x - NCHP;
        __shared__ float emb[128];
        if (tid < 128) {
            const float kStep = 9.210340371976184f / 63.0f;
            int k = tid & 63;
            float ang = t[b] * expf(-(float)k * kStep);
            emb[tid] = (tid < 64) ? sinf(ang) : cosf(ang);
        }
        __syncthreads();
        for (int j = tid; j < 512; j += 256) {
            float a = 0.f;
            for (int k = 0; k < 128; ++k) a += emb[k] * W1[k * 512 + j];
            h1acc[b * 512 + j] = a;        // pre-bias/swish
            h2acc[b * 512 + j] = 0.f;
        }
        if (tid < 32) inj[b * 32 + tid] = 0.f;
        return;
    }
    __shared__ int h[NBCMAX];
    int c = blockIdx.x;
    for (int i = tid; i < NBC; i += 256) h[i] = 0;
    __syncthreads();
    int* rep = nodeRep + (size_t)(blockIdx.x & 7) * N;   // per-XCD replica
    int s = c * CH, e = min(s + CH, E);
    int nfull = (e - s) & ~3;
    for (int i0 = s + tid * 4; i0 < s + nfull; i0 += 1024) {
        int4 r4 = *(const int4*)&ei[i0];
        atomicAdd(&h[r4.x >> CWSH], 1);
        atomicAdd(&h[r4.y >> CWSH], 1);
        atomicAdd(&h[r4.z >> CWSH], 1);
        atomicAdd(&h[r4.w >> CWSH], 1);
        atomicAdd(&rep[r4.x], 1);
        atomicAdd(&rep[r4.y], 1);
        atomicAdd(&rep[r4.z], 1);
        atomicAdd(&rep[r4.w], 1);
    }
    for (int i = s + nfull + tid; i < e; i += 256) {
        int row = ei[i];
        atomicAdd(&h[row >> CWSH], 1);
        atomicAdd(&rep[row], 1);
    }
    __syncthreads();
    int* rowp = counts + (size_t)c * NBC;
    for (int b = tid; b < NBC; b += 256) rowp[b] = h[b];
    // x -> fp16 slice (independent of hist)
    int per = (N + NCHP - 1) / NCHP;
    int n0 = c * per, n1 = min(n0 + per, N);
    for (int n = n0 + tid; n < n1; n += 256) {
        float4 v = ((const float4*)x)[n];
        uint2 p;
        p.x = pack2(v.x, v.y);
        p.y = pack2(v.z, v.w);
        xh[n] = p;
    }
}

// ---- scanA: per-block sums (j=(b<<LOGC)+c); extra 64 blocks = temb stage2 -
__global__ __launch_bounds__(256) void scanA_kernel(
    const int* __restrict__ counts, int* __restrict__ bsums,
    const float* __restrict__ h1acc, const float* __restrict__ b1,
    const float* __restrict__ W2, float* __restrict__ h2acc,
    int M, int NBC, int LOGC, int nblkA)
{
    int tid = threadIdx.x;
    if ((int)blockIdx.x >= nblkA) {
        int p = blockIdx.x - nblkA;            // k-slice [8p, 8p+8)
        __shared__ float h1s[64];              // [b*8+kk]
        if (tid < 64) {
            int bb = tid >> 3, kk = tid & 7;
            int k = p * 8 + kk;
            float v = h1acc[bb * 512 + k] + b1[k];
            h1s[tid] = v / (1.f + expf(-v));
        }
        __syncthreads();
        for (int jj = 0; jj < 2; ++jj) {
            int j = tid + jj * 256;
            float acc[8] = {};
#pragma unroll
            for (int kk = 0; kk < 8; ++kk) {
                float w = W2[(p * 8 + kk) * 512 + j];
#pragma unroll
                for (int bb = 0; bb < 8; ++bb) acc[bb] += h1s[bb * 8 + kk] * w;
            }
#pragma unroll
            for (int bb = 0; bb < 8; ++bb)
                atomicAdd(&h2acc[bb * 512 + j], acc[bb]);
        }
        return;
    }
    __shared__ int s[256];
    int j0 = blockIdx.x * 4096 + tid * 16;
    int maskC = (1 << LOGC) - 1;
    int p = 0;
#pragma unroll
    for (int k = 0; k < 16; ++k) {
        int j = j0 + k;
        if (j < M) {
            int b = j >> LOGC, c = j & maskC;
            p += counts[(size_t)c * NBC + b];
        }
    }
    s[tid] = p; __syncthreads();
    for (int off = 128; off > 0; off >>= 1) {
        if (tid < off) s[tid] += s[tid + off];
        __syncthreads();
    }
    if (tid == 0) bsums[blockIdx.x] = s[0];
}

// ---- scanB: exclusive scan of block sums (single block) -------------------
__global__ __launch_bounds__(1024) void scanB_kernel(
    int* __restrict__ bsums, int* __restrict__ bstart, int nblk, int NBC, int E)
{
    __shared__ int s[1024];
    int tid = threadIdx.x;
    int v = (tid < nblk) ? bsums[tid] : 0;
    s[tid] = v; __syncthreads();
    for (int off = 1; off < 1024; off <<= 1) {
        int u = (tid >= off) ? s[tid - off] : 0;
        __syncthreads();
        s[tid] += u;
        __syncthreads();
    }
    if (tid < nblk) bsums[tid] = s[tid] - v;          // exclusive
    if (tid == 0) bstart[NBC] = E;
}

// ---- scanC: per-(bucket,chunk) bases + bstart; extra 8 blocks = stage3 ----
__global__ __launch_bounds__(256) void scanC_kernel(
    const int* __restrict__ counts, const int* __restrict__ bsums,
    int* __restrict__ base, int* __restrict__ bstart,
    const float* __restrict__ h2acc, const float* __restrict__ b2,
    const float* __restrict__ Wt, float* __restrict__ inj,
    int M, int NBC, int LOGC, int nblkA)
{
    int tid = threadIdx.x;
    if ((int)blockIdx.x >= nblkA) {
        int ks = blockIdx.x - nblkA;
        __shared__ float sws[8][64];
        for (int i = tid; i < 512; i += 256) {
            int b = i >> 6, kk = i & 63;
            int k = ks * 64 + kk;
            float v = h2acc[b * 512 + k] + b2[k];
            sws[b][kk] = v / (1.f + expf(-v));
        }
        __syncthreads();
        int b = tid >> 5, c = tid & 31;
        float acc = 0.f;
        for (int kk = 0; kk < 64; ++kk)
            acc += sws[b][kk] * Wt[(ks * 64 + kk) * 32 + c];
        atomicAdd(&inj[tid], acc);
        return;
    }
    __shared__ int s[256];
    int j0 = blockIdx.x * 4096 + tid * 16;
    int maskC = (1 << LOGC) - 1;
    int v[16]; int p = 0;
#pragma unroll
    for (int k = 0; k < 16; ++k) {
        int j = j0 + k;
        v[k] = 0;
        if (j < M) {
            int b = j >> LOGC, c = j & maskC;
            v[k] = counts[(size_t)c * NBC + b];
        }
        p += v[k];
    }
    s[tid] = p; __syncthreads();
    for (int off = 1; off < 256; off <<= 1) {
        int u = (tid >= off) ? s[tid - off] : 0;
        __syncthreads();
        s[tid] += u;
        __syncthreads();
    }
    int run = bsums[blockIdx.x] + (s[tid] - p);
#pragma unroll
    for (int k = 0; k < 16; ++k) {
        int j = j0 + k;
        if (j < M) {
            base[j] = run;
            if ((j & maskC) == 0) bstart[j >> LOGC] = run;
            run += v[k];
        }
    }
}

// ---- scatter: block per chunk; XCD swizzle; int4 loads; 8B recs -----------
// rec = { col | T<<19 | nt<<22 , row & (CW-1) }
__global__ __launch_bounds__(512) void scatter_kernel(
    const int* __restrict__ ei, const int* __restrict__ etype,
    const int* __restrict__ ntype, const int* __restrict__ base,
    uint2* __restrict__ rec, int E, int NBC, int LOGC)
{
    __shared__ int cur[NBCMAX];
    int tid = threadIdx.x;
    int nwg = gridDim.x;
    int q = nwg >> 3, r = nwg & 7;
    int xcd = blockIdx.x & 7, idx = blockIdx.x >> 3;
    int c = (xcd < r) ? xcd * (q + 1) + idx
                      : r * (q + 1) + (xcd - r) * q + idx;
    for (int b = tid; b < NBC; b += 512)
        cur[b] = base[((size_t)b << LOGC) + c];
    __syncthreads();
    int s = c * CH, e = min(s + CH, E);
    int nfull = (e - s) & ~3;
    for (int i0 = s + tid * 4; i0 < s + nfull; i0 += 2048) {
        int4 r4 = *(const int4*)&ei[i0];
        int4 c4 = *(const int4*)&ei[E + i0];
        int4 t4 = *(const int4*)&etype[i0];
#pragma unroll
        for (int k = 0; k < 4; ++k) {
            int row = (&r4.x)[k], col = (&c4.x)[k], T = (&t4.x)[k];
            int nt = ntype[col];
            int b = row >> CWSH;
            int slot = atomicAdd(&cur[b], 1);
            uint2 rc;
            rc.x = (unsigned)col | ((unsigned)T << 19) | ((unsigned)nt << 22);
            rc.y = (unsigned)(row & (CW - 1));
            rec[slot] = rc;
        }
    }
    for (int i = s + nfull + tid; i < e; i += 512) {
        int row = ei[i], col = ei[E + i];
        int T = etype[i], nt = ntype[col];
        int b = row >> CWSH;
        int slot = atomicAdd(&cur[b], 1);
        uint2 rc;
        rc.x = (unsigned)col | ((unsigned)T << 19) | ((unsigned)nt << 22);
        rc.y = (unsigned)(row & (CW - 1));
        rec[slot] = rc;
    }
}

// ---- repack: block per coarse bucket; SINGLE pass (hist from replicas) ----
__global__ __launch_bounds__(1024) void repack_kernel(
    const int* __restrict__ bstart, const int* __restrict__ nodeRep,
    const uint2* __restrict__ rec, unsigned* __restrict__ rec2,
    int* __restrict__ nodeStart, int NBC, int N, int E)
{
    __shared__ int hist[CW];     // abs starts -> cursors
    __shared__ int sc[1024];
    int tid = threadIdx.x;
    int b = blockIdx.x;
    int nbase = b * CW;
    int s = bstart[b], e = bstart[b + 1];
    // per-node counts from the 8 XCD replicas (sequential reads)
    int n0 = nbase + 2 * tid, n1 = n0 + 1;
    int c0 = 0, c1 = 0;
#pragma unroll
    for (int r = 0; r < 8; ++r) {
        const int* rp = nodeRep + (size_t)r * N;
        if (n0 < N) c0 += rp[n0];
        if (n1 < N) c1 += rp[n1];
    }
    int tsum = c0 + c1;
    sc[tid] = tsum; __syncthreads();
    for (int off = 1; off < 1024; off <<= 1) {
        int u = (tid >= off) ? sc[tid - off] : 0;
        __syncthreads();
        sc[tid] += u;
        __syncthreads();
    }
    int excl = sc[tid] - tsum;
    hist[2 * tid]     = s + excl;           // absolute start
    hist[2 * tid + 1] = s + excl + c0;
    __syncthreads();
    // write nodeStart for this bucket's nodes
    for (int l = tid; l < CW; l += 1024) {
        int n = nbase + l;
        if (n < N) nodeStart[n] = hist[l];
    }
    if (b == NBC - 1 && tid == 0) nodeStart[N] = E;
    __syncthreads();
    // cursor scatter into node order; drop lrow (position encodes it)
    for (int i = s + tid; i < e; i += 1024) {
        uint2 rc = rec[i];
        int slot = atomicAdd(&hist[rc.y], 1);
        rec2[slot] = rc.x;                  // col | T<<19 | nt<<22
    }
}

// ---- consume: 512thr/128 nodes; 4-way replica record split + LDS combine --
__global__ __launch_bounds__(512) void consume_kernel(
    const int* __restrict__ nodeStart, const unsigned* __restrict__ rec2,
    const uint2* __restrict__ xh, const float* __restrict__ Wc,
    const int* __restrict__ batch, const float* __restrict__ inj,
    float* __restrict__ out, int N)
{
    __shared__ int seg[WSZ + 1];
    __shared__ unsigned sbuf[3 * CAP];      // smeta | sx01 | sx23, then red
    unsigned* smeta = sbuf;
    unsigned* sx01  = sbuf + CAP;
    unsigned* sx23  = sbuf + 2 * CAP;
    int tid = threadIdx.x;
    int f = blockIdx.x;
    int node0 = f << WSH;
    int nodes = N - node0; if (nodes > WSZ) nodes = WSZ;

    for (int i = tid; i <= nodes; i += 512) seg[i] = nodeStart[node0 + i];
    __syncthreads();
    int s = seg[0], e = seg[nodes];

    int nl = tid & (WSZ - 1);
    int rep = tid >> 7;                    // 0..3, wave-uniform
    int myS = (nl < nodes) ? seg[nl] : e;
    int myE = (nl < nodes) ? seg[nl + 1] : e;

    float acc[20] = {};                    // [T][0..3] x-sums
    int cnt0[5] = {}, cnt1[5] = {};        // 8-bit packed nt counts
    for (int base = s; base < e; base += CAP) {
        int w = e - base; if (w > CAP) w = CAP;
        __syncthreads();                   // protect stage reuse
        for (int i = tid; i < w; i += 512) {
            unsigned u = rec2[base + i];
            smeta[i] = u;
            uint2 p = xh[u & 0x7FFFFu];
            sx01[i] = p.x;
            sx23[i] = p.y;
        }
        __syncthreads();
        // replica rep handles j = myS + rep + 4k
        int jstart = myS + rep;
        if (jstart < base)
            jstart += ((base - jstart + 3) >> 2) << 2;
        int jend = myE < base + w ? myE : base + w;
        for (int j = jstart; j < jend; j += 4) {
            int k = j - base;
            unsigned u = smeta[k];
            int T  = (int)((u >> 19) & 7u);
            int nt = (int)((u >> 22) & 7u);
            float2 x01 = unpack2(sx01[k]);
            float2 x23 = unpack2(sx23[k]);
            int lob = (nt < 4) ? (1 << (nt * 8)) : 0;
            int hib = (nt >= 4) ? (1 << ((nt - 4) * 8)) : 0;
#pragma unroll
            for (int tt = 0; tt < 5; ++tt) {
                bool m = (T == tt);
                acc[tt * 4 + 0] += m ? x01.x : 0.f;
                acc[tt * 4 + 1] += m ? x01.y : 0.f;
                acc[tt * 4 + 2] += m ? x23.x : 0.f;
                acc[tt * 4 + 3] += m ? x23.y : 0.f;
                cnt0[tt] += m ? lob : 0;
                cnt1[tt] += m ? hib : 0;
            }
        }
    }

    // combine the 4 replica partials: 3 passes of 10 values via sbuf reuse
    // slot stride 43 (odd, coprime 32) -> conflict-free
    {
        float* redf = (float*)sbuf;
        int*   redi = (int*)sbuf;
        int wslot = nl * 43 + rep * 10;
        int rbase = nl * 43;
#pragma unroll
        for (int p = 0; p < 3; ++p) {
            __syncthreads();
            if (p < 2) {
#pragma unroll
                for (int i = 0; i < 10; ++i) redf[wslot + i] = acc[p * 10 + i];
            } else {
#pragma unroll
                for (int i = 0; i < 5; ++i) {
                    redi[wslot + i]     = cnt0[i];
                    redi[wslot + 5 + i] = cnt1[i];
                }
            }
            __syncthreads();
            if (p < 2) {
#pragma unroll
                for (int i = 0; i < 10; ++i)
                    acc[p * 10 + i] = redf[rbase + i] + redf[rbase + 10 + i] +
                                      redf[rbase + 20 + i] + redf[rbase + 30 + i];
            } else {
#pragma unroll
                for (int i = 0; i < 5; ++i) {
                    cnt0[i] = redi[rbase + i] + redi[rbase + 10 + i] +
                              redi[rbase + 20 + i] + redi[rbase + 30 + i];
                    cnt1[i] = redi[rbase + 5 + i] + redi[rbase + 15 + i] +
                              redi[rbase + 25 + i] + redi[rbase + 35 + i];
                }
            }
        }
    }

    if (nl < nodes) {
        int hf = __builtin_amdgcn_readfirstlane(rep);        // 0..3
        const float4* wq = (const float4*)Wc;
        float4 o0 = {0.f, 0.f, 0.f, 0.f}, o1 = o0;
#pragma unroll
        for (int f2 = 0; f2 < 55; ++f2) {
            const int tt = f2 / 11, j = f2 % 11;
            float a;
            if (j < 4) a = acc[tt * 4 + j];
            else {
                const int kk = j - 4;
                a = (kk < 4) ? (float)((cnt0[tt] >> (kk * 8)) & 255)
                             : (float)((cnt1[tt] >> ((kk - 4) * 8)) & 255);
            }
            float4 w0 = wq[f2 * 8 + hf * 2];
            float4 w1 = wq[f2 * 8 + hf * 2 + 1];
            o0.x += a * w0.x; o0.y += a * w0.y; o0.z += a * w0.z; o0.w += a * w0.w;
            o1.x += a * w1.x; o1.y += a * w1.y; o1.z += a * w1.z; o1.w += a * w1.w;
        }
        int n = node0 + nl;
        int bb = batch[n];
        const float4* iv = ((const float4*)inj) + bb * 8 + hf * 2;
        float4 i0 = iv[0], i1 = iv[1];
        float4 r0, r1;
        r0.x = i0.x + 0.2f * o0.x; r0.y = i0.y + 0.2f * o0.y;
        r0.z = i0.z + 0.2f * o0.z; r0.w = i0.w + 0.2f * o0.w;
        r1.x = i1.x + 0.2f * o1.x; r1.y = i1.y + 0.2f * o1.y;
        r1.z = i1.z + 0.2f * o1.z; r1.w = i1.w + 0.2f * o1.w;
        float4* op = ((float4*)out) + (size_t)n * 8 + hf * 2;
        op[0] = r0; op[1] = r1;
    }
}

// ---- fallback: fused temb + init + direct atomic scatter ------------------
__global__ __launch_bounds__(256) void temb_fused_kernel(
    const float* __restrict__ t,
    const float* __restrict__ W1, const float* __restrict__ b1,
    const float* __restrict__ W2, const float* __restrict__ b2,
    const float* __restrict__ Wt, float* __restrict__ inj)
{
    int b = blockIdx.x;
    int tid = threadIdx.x;
    __shared__ float emb[128];
    __shared__ float s1[512];
    __shared__ float s2[512];
    __shared__ float red[256];
    float tv = t[b];
    if (tid < 128) {
        const float kStep = 9.210340371976184f / 63.0f;
        int k = tid & 63;
        float ang = tv * expf(-(float)k * kStep);
        emb[tid] = (tid < 64) ? sinf(ang) : cosf(ang);
    }
    __syncthreads();
    {
        float a0 = 0.f, a1 = 0.f;
        for (int k = 0; k < 128; ++k) {
            float e = emb[k];
            a0 += e * W1[k * 512 + tid];
            a1 += e * W1[k * 512 + tid + 256];
        }
        float v0 = a0 + b1[tid], v1 = a1 + b1[tid + 256];
        s1[tid]       = v0 / (1.0f + expf(-v0));
        s1[tid + 256] = v1 / (1.0f + expf(-v1));
    }
    __syncthreads();
    {
        float a0 = 0.f, a1 = 0.f;
        for (int k = 0; k < 512; ++k) {
            float e = s1[k];
            a0 += e * W2[k * 512 + tid];
            a1 += e * W2[k * 512 + tid + 256];
        }
        float v0 = a0 + b2[tid], v1 = a1 + b2[tid + 256];
        s2[tid]       = v0 / (1.0f + expf(-v0));
        s2[tid + 256] = v1 / (1.0f + expf(-v1));
    }
    __syncthreads();
    {
        int c = tid & 31, seg = tid >> 5;
        float acc = 0.f;
        int k0 = seg * 64;
        for (int k = k0; k < k0 + 64; ++k)
            acc += s2[k] * Wt[k * 32 + c];
        red[tid] = acc;
        __syncthreads();
        if (tid < 32) {
            float s = 0.f;
#pragma unroll
            for (int g = 0; g < 8; ++g) s += red[g * 32 + tid];
            inj[b * 32 + tid] = s;
        }
    }
}

__global__ __launch_bounds__(256) void init_kernel(
    const int* __restrict__ batch_id, const float* __restrict__ inj,
    float4* __restrict__ out, int N)
{
    int gid = blockIdx.x * 256 + threadIdx.x;
    if (gid >= N * 8) return;
    int n = gid >> 3, q = gid & 7;
    int b = batch_id[n];
    out[gid] = ((const float4*)inj)[b * 8 + q];
}

__global__ __launch_bounds__(256) void edge_direct_kernel(
    const int* __restrict__ ei, const int* __restrict__ etype,
    const int* __restrict__ ntype, const float* __restrict__ x,
    const float* __restrict__ Wc, float* __restrict__ out, int E)
{
    __shared__ float Ws[55 * 32];
    for (int i = threadIdx.x; i < 55 * 32; i += 256) Ws[i] = Wc[i];
    __syncthreads();
    unsigned total = (unsigned)E * 32u;
    unsigned stride = gridDim.x * 256u;
    for (unsigned idx = blockIdx.x * 256u + threadIdx.x; idx < total;
         idx += stride) {
        int e = (int)(idx >> 5);
        int c = (int)(idx & 31);
        int row = ei[e];
        int col = ei[E + e];
        int T = etype[e];
        int nt = ntype[col];
        float4 xv = ((const float4*)x)[col];
        const float* wb = Ws + T * 352;
        float y = xv.x * wb[c] + xv.y * wb[32 + c] + xv.z * wb[64 + c] +
                  xv.w * wb[96 + c] + wb[(4 + nt) * 32 + c];
        atomicAdd(out + (size_t)row * 32 + c, y * 0.2f);
    }
}

extern "C" void kernel_launch(void* const* d_in, const int* in_sizes, int n_in,
                              void* d_out, int out_size, void* d_ws, size_t ws_size,
                              hipStream_t stream) {
    const float* x     = (const float*)d_in[0];   // [N,4]
    const float* t     = (const float*)d_in[1];   // [8]
    const int*   ei    = (const int*)d_in[2];     // [2,E]
    const int*   etype = (const int*)d_in[3];     // [E]
    const int*   ntype = (const int*)d_in[4];     // [N]
    const int*   batch = (const int*)d_in[5];     // [N]
    const float* Wc    = (const float*)d_in[6];   // [55,32]
    const float* W1    = (const float*)d_in[7];   // [128,512]
    const float* b1    = (const float*)d_in[8];   // [512]
    const float* W2    = (const float*)d_in[9];   // [512,512]
    const float* b2    = (const float*)d_in[10];  // [512]
    const float* Wt    = (const float*)d_in[11];  // [512,32]
    float* out = (float*)d_out;

    int E = in_sizes[3];
    int N = in_sizes[4];

    int NBC = (N + CW - 1) >> CWSH;               // coarse buckets
    int NFr = (N + WSZ - 1) >> WSH;               // consume blocks
    int NCH = (E + CH - 1) / CH;
    int NCHP = 1, LOGC = 0;
    while (NCHP < NCH) { NCHP <<= 1; ++LOGC; }
    size_t M = (size_t)NBC << LOGC;
    int nblkA = (int)((M + 4095) / 4096);

    // ws layout (4-byte units)
    float* ws     = (float*)d_ws;
    float* h1acc  = ws;                           // 4096
    float* h2acc  = ws + 4096;                    // 4096
    float* inj    = ws + 8192;                    // 256
    uint2* xh     = (uint2*)(ws + 8448);          // 2N words
    int*   nodeRep = (int*)(ws + 8448 + 2 * (size_t)N);  // 8N words
    int*   counts = nodeRep + 8 * (size_t)N;      // M
    int*   base   = counts + M;                   // M
    int*   bsums  = base + M;                     // 1024
    int*   bstart = bsums + 1024;                 // NBC+1
    int*   nodeSt = bstart + NBC + 1;             // N+1
    size_t recOff = 8448 + 2 * (size_t)N + 8 * (size_t)N + 2 * M + 1024 +
                    (NBC + 1) + ((size_t)N + 1);
    recOff = (recOff + 1) & ~(size_t)1;           // 8B align
    uint2*    rec  = (uint2*)(ws + recOff);       // 2E words
    unsigned* rec2 = (unsigned*)(ws + recOff + 2 * (size_t)E);  // E words

    size_t needBytes = (recOff + 3 * (size_t)E) * 4;
    bool okay = (NBC <= NBCMAX) && (nblkA <= 1024) && (ws_size >= needBytes) &&
                (N <= NBCMAX * CW) && ((E & 3) == 0) && (M < (size_t)1 << 30);

    if (okay) {
        hipMemsetAsync(nodeRep, 0, 8 * (size_t)N * 4, stream);

        histW_kernel<<<NCHP + 8, 256, 0, stream>>>(
            ei, counts, nodeRep, x, xh, t, W1, h1acc, h2acc, inj,
            E, N, NBC, NCHP);
        scanA_kernel<<<nblkA + 64, 256, 0, stream>>>(
            counts, bsums, h1acc, b1, W2, h2acc, (int)M, NBC, LOGC, nblkA);
        scanB_kernel<<<1, 1024, 0, stream>>>(bsums, bstart, nblkA, NBC, E);
        scanC_kernel<<<nblkA + 8, 256, 0, stream>>>(
            counts, bsums, base, bstart, h2acc, b2, Wt, inj,
            (int)M, NBC, LOGC, nblkA);
        scatter_kernel<<<NCH, 512, 0, stream>>>(
            ei, etype, ntype, base, rec, E, NBC, LOGC);
        repack_kernel<<<NBC, 1024, 0, stream>>>(
            bstart, nodeRep, rec, rec2, nodeSt, NBC, N, E);
        consume_kernel<<<NFr, 512, 0, stream>>>(
            nodeSt, rec2, xh, Wc, batch, inj, out, N);
    } else {
        temb_fused_kernel<<<8, 256, 0, stream>>>(t, W1, b1, W2, b2, Wt, inj);
        init_kernel<<<(N * 8 + 255) / 256, 256, 0, stream>>>(
            batch, inj, (float4*)out, N);
        edge_direct_kernel<<<16384, 256, 0, stream>>>(
            ei, etype, ntype, x, Wc, out, E);
    }
}

// Round 12
// 225.490 us; speedup vs baseline: 1.3118x; 1.3118x over previous
//
#include <hip/hip_runtime.h>
#include <hip/hip_fp16.h>

// ---------------------------------------------------------------------------
// N=400000, E=2000000, B=8, C_IN=4, N_EDGE_TYPE=5, N_NODE_TYPE=7, C_OUT=32.
//
// HW model (measured, rounds 0-11):
//  - GLOBAL atomics are DEVICE-SCOPE: they execute at the cross-XCD
//    coherence point, never in the local L2. Per-XCD "replica" tricks are
//    impossible (R11: 2M spread atomics -> 66MB writes, +60us). Avoid
//    global atomics in hot paths entirely.
//  - Write-merge RULE: regions >= ~64B or write-allocate amplification (R3).
//  - consume's 80us floor WAS the 10M LDS atomics (R10: removal -> 58us,
//    VALUBusy 13->79%). Now VALU-bound: 4x-redundant replica accumulate.
//  => R12: R10 champion restored verbatim (repack owns its LDS node-hist,
//     CH=4096), + ONE change: consume splits records across the 4
//     hf-replicas (j = myS+rep mod 4) with a 3-pass stride-43 LDS combine.
// ---------------------------------------------------------------------------

#define CH      4096       // edges per chunk
#define CW      2048       // coarse bucket width (nodes)
#define CWSH    11         // log2(CW)
#define WSZ     128        // consume window (nodes)
#define WSH     7          // log2(WSZ)
#define NBCMAX  512        // max coarse buckets
#define CAP     2048       // consume stage capacity (records)

__device__ __forceinline__ unsigned pack2(float a, float b) {
    __half2 h = __floats2half2_rn(a, b);
    union { __half2 h; unsigned u; } cv; cv.h = h; return cv.u;
}
__device__ __forceinline__ float2 unpack2(unsigned u) {
    union { unsigned u; __half2 h; } cv; cv.u = u;
    return __half22float2(cv.h);
}

// ---- histW: chunk blocks: coarse LDS hist (int4 loads) + x->fp16 slice.
// ---- extra 8 blocks: temb stage1 (h1 = emb@W1; zero h2acc/inj) -----------
__global__ __launch_bounds__(256) void histW_kernel(
    const int* __restrict__ ei, int* __restrict__ counts,
    const float* __restrict__ x, uint2* __restrict__ xh,
    const float* __restrict__ t, const float* __restrict__ W1,
    float* __restrict__ h1acc, float* __restrict__ h2acc,
    float* __restrict__ inj,
    int E, int N, int NBC, int NCHP)
{
    int tid = threadIdx.x;
    if ((int)blockIdx.x >= NCHP) {
        int b = blockIdx.x - NCHP;
        __shared__ float emb[128];
        if (tid < 128) {
            const float kStep = 9.210340371976184f / 63.0f;
            int k = tid & 63;
            float ang = t[b] * expf(-(float)k * kStep);
            emb[tid] = (tid < 64) ? sinf(ang) : cosf(ang);
        }
        __syncthreads();
        for (int j = tid; j < 512; j += 256) {
            float a = 0.f;
            for (int k = 0; k < 128; ++k) a += emb[k] * W1[k * 512 + j];
            h1acc[b * 512 + j] = a;        // pre-bias/swish
            h2acc[b * 512 + j] = 0.f;
        }
        if (tid < 32) inj[b * 32 + tid] = 0.f;
        return;
    }
    __shared__ int h[NBCMAX];
    int c = blockIdx.x;
    for (int i = tid; i < NBC; i += 256) h[i] = 0;
    __syncthreads();
    int s = c * CH, e = min(s + CH, E);
    int nfull = (e - s) & ~3;
    for (int i0 = s + tid * 4; i0 < s + nfull; i0 += 1024) {
        int4 r4 = *(const int4*)&ei[i0];
        atomicAdd(&h[r4.x >> CWSH], 1);
        atomicAdd(&h[r4.y >> CWSH], 1);
        atomicAdd(&h[r4.z >> CWSH], 1);
        atomicAdd(&h[r4.w >> CWSH], 1);
    }
    for (int i = s + nfull + tid; i < e; i += 256)
        atomicAdd(&h[ei[i] >> CWSH], 1);
    __syncthreads();
    int* row = counts + (size_t)c * NBC;
    for (int b = tid; b < NBC; b += 256) row[b] = h[b];
    // x -> fp16 slice (independent of hist)
    int per = (N + NCHP - 1) / NCHP;
    int n0 = c * per, n1 = min(n0 + per, N);
    for (int n = n0 + tid; n < n1; n += 256) {
        float4 v = ((const float4*)x)[n];
        uint2 p;
        p.x = pack2(v.x, v.y);
        p.y = pack2(v.z, v.w);
        xh[n] = p;
    }
}

// ---- scanA: per-block sums (j=(b<<LOGC)+c); extra 64 blocks = temb stage2 -
__global__ __launch_bounds__(256) void scanA_kernel(
    const int* __restrict__ counts, int* __restrict__ bsums,
    const float* __restrict__ h1acc, const float* __restrict__ b1,
    const float* __restrict__ W2, float* __restrict__ h2acc,
    int M, int NBC, int LOGC, int nblkA)
{
    int tid = threadIdx.x;
    if ((int)blockIdx.x >= nblkA) {
        int p = blockIdx.x - nblkA;            // k-slice [8p, 8p+8)
        __shared__ float h1s[64];              // [b*8+kk]
        if (tid < 64) {
            int bb = tid >> 3, kk = tid & 7;
            int k = p * 8 + kk;
            float v = h1acc[bb * 512 + k] + b1[k];
            h1s[tid] = v / (1.f + expf(-v));
        }
        __syncthreads();
        for (int jj = 0; jj < 2; ++jj) {
            int j = tid + jj * 256;
            float acc[8] = {};
#pragma unroll
            for (int kk = 0; kk < 8; ++kk) {
                float w = W2[(p * 8 + kk) * 512 + j];
#pragma unroll
                for (int bb = 0; bb < 8; ++bb) acc[bb] += h1s[bb * 8 + kk] * w;
            }
#pragma unroll
            for (int bb = 0; bb < 8; ++bb)
                atomicAdd(&h2acc[bb * 512 + j], acc[bb]);
        }
        return;
    }
    __shared__ int s[256];
    int j0 = blockIdx.x * 4096 + tid * 16;
    int maskC = (1 << LOGC) - 1;
    int p = 0;
#pragma unroll
    for (int k = 0; k < 16; ++k) {
        int j = j0 + k;
        if (j < M) {
            int b = j >> LOGC, c = j & maskC;
            p += counts[(size_t)c * NBC + b];
        }
    }
    s[tid] = p; __syncthreads();
    for (int off = 128; off > 0; off >>= 1) {
        if (tid < off) s[tid] += s[tid + off];
        __syncthreads();
    }
    if (tid == 0) bsums[blockIdx.x] = s[0];
}

// ---- scanB: exclusive scan of block sums (single block) -------------------
__global__ __launch_bounds__(1024) void scanB_kernel(
    int* __restrict__ bsums, int* __restrict__ bstart, int nblk, int NBC, int E)
{
    __shared__ int s[1024];
    int tid = threadIdx.x;
    int v = (tid < nblk) ? bsums[tid] : 0;
    s[tid] = v; __syncthreads();
    for (int off = 1; off < 1024; off <<= 1) {
        int u = (tid >= off) ? s[tid - off] : 0;
        __syncthreads();
        s[tid] += u;
        __syncthreads();
    }
    if (tid < nblk) bsums[tid] = s[tid] - v;          // exclusive
    if (tid == 0) bstart[NBC] = E;
}

// ---- scanC: per-(bucket,chunk) bases + bstart; extra 8 blocks = stage3 ----
__global__ __launch_bounds__(256) void scanC_kernel(
    const int* __restrict__ counts, const int* __restrict__ bsums,
    int* __restrict__ base, int* __restrict__ bstart,
    const float* __restrict__ h2acc, const float* __restrict__ b2,
    const float* __restrict__ Wt, float* __restrict__ inj,
    int M, int NBC, int LOGC, int nblkA)
{
    int tid = threadIdx.x;
    if ((int)blockIdx.x >= nblkA) {
        int ks = blockIdx.x - nblkA;
        __shared__ float sws[8][64];
        for (int i = tid; i < 512; i += 256) {
            int b = i >> 6, kk = i & 63;
            int k = ks * 64 + kk;
            float v = h2acc[b * 512 + k] + b2[k];
            sws[b][kk] = v / (1.f + expf(-v));
        }
        __syncthreads();
        int b = tid >> 5, c = tid & 31;
        float acc = 0.f;
        for (int kk = 0; kk < 64; ++kk)
            acc += sws[b][kk] * Wt[(ks * 64 + kk) * 32 + c];
        atomicAdd(&inj[tid], acc);
        return;
    }
    __shared__ int s[256];
    int j0 = blockIdx.x * 4096 + tid * 16;
    int maskC = (1 << LOGC) - 1;
    int v[16]; int p = 0;
#pragma unroll
    for (int k = 0; k < 16; ++k) {
        int j = j0 + k;
        v[k] = 0;
        if (j < M) {
            int b = j >> LOGC, c = j & maskC;
            v[k] = counts[(size_t)c * NBC + b];
        }
        p += v[k];
    }
    s[tid] = p; __syncthreads();
    for (int off = 1; off < 256; off <<= 1) {
        int u = (tid >= off) ? s[tid - off] : 0;
        __syncthreads();
        s[tid] += u;
        __syncthreads();
    }
    int run = bsums[blockIdx.x] + (s[tid] - p);
#pragma unroll
    for (int k = 0; k < 16; ++k) {
        int j = j0 + k;
        if (j < M) {
            base[j] = run;
            if ((j & maskC) == 0) bstart[j >> LOGC] = run;
            run += v[k];
        }
    }
}

// ---- scatter: block per chunk; XCD swizzle; int4 loads; 8B recs -----------
// rec = { col | T<<19 | nt<<22 , row & (CW-1) }
__global__ __launch_bounds__(512) void scatter_kernel(
    const int* __restrict__ ei, const int* __restrict__ etype,
    const int* __restrict__ ntype, const int* __restrict__ base,
    uint2* __restrict__ rec, int E, int NBC, int LOGC)
{
    __shared__ int cur[NBCMAX];
    int tid = threadIdx.x;
    int nwg = gridDim.x;
    int q = nwg >> 3, r = nwg & 7;
    int xcd = blockIdx.x & 7, idx = blockIdx.x >> 3;
    int c = (xcd < r) ? xcd * (q + 1) + idx
                      : r * (q + 1) + (xcd - r) * q + idx;
    for (int b = tid; b < NBC; b += 512)
        cur[b] = base[((size_t)b << LOGC) + c];
    __syncthreads();
    int s = c * CH, e = min(s + CH, E);
    int nfull = (e - s) & ~3;
    for (int i0 = s + tid * 4; i0 < s + nfull; i0 += 2048) {
        int4 r4 = *(const int4*)&ei[i0];
        int4 c4 = *(const int4*)&ei[E + i0];
        int4 t4 = *(const int4*)&etype[i0];
#pragma unroll
        for (int k = 0; k < 4; ++k) {
            int row = (&r4.x)[k], col = (&c4.x)[k], T = (&t4.x)[k];
            int nt = ntype[col];
            int b = row >> CWSH;
            int slot = atomicAdd(&cur[b], 1);
            uint2 rc;
            rc.x = (unsigned)col | ((unsigned)T << 19) | ((unsigned)nt << 22);
            rc.y = (unsigned)(row & (CW - 1));
            rec[slot] = rc;
        }
    }
    for (int i = s + nfull + tid; i < e; i += 512) {
        int row = ei[i], col = ei[E + i];
        int T = etype[i], nt = ntype[col];
        int b = row >> CWSH;
        int slot = atomicAdd(&cur[b], 1);
        uint2 rc;
        rc.x = (unsigned)col | ((unsigned)T << 19) | ((unsigned)nt << 22);
        rc.y = (unsigned)(row & (CW - 1));
        rec[slot] = rc;
    }
}

// ---- repack: block per coarse bucket; NODE-level sort; writes nodeStart ---
__global__ __launch_bounds__(1024) void repack_kernel(
    const int* __restrict__ bstart, const uint2* __restrict__ rec,
    unsigned* __restrict__ rec2, int* __restrict__ nodeStart,
    int NBC, int N, int E)
{
    __shared__ int hist[CW];     // per-node counts -> abs starts -> cursors
    __shared__ int sc[1024];
    int tid = threadIdx.x;
    int b = blockIdx.x;
    for (int i = tid; i < CW; i += 1024) hist[i] = 0;
    __syncthreads();
    int s = bstart[b], e = bstart[b + 1];
    for (int i = s + tid; i < e; i += 1024)
        atomicAdd(&hist[rec[i].y], 1);
    __syncthreads();
    // exclusive scan of hist[2048]: 2 elems/thread + Hillis-Steele over 1024
    int a0 = hist[2 * tid], a1 = hist[2 * tid + 1];
    int tsum = a0 + a1;
    sc[tid] = tsum; __syncthreads();
    for (int off = 1; off < 1024; off <<= 1) {
        int u = (tid >= off) ? sc[tid - off] : 0;
        __syncthreads();
        sc[tid] += u;
        __syncthreads();
    }
    int excl = sc[tid] - tsum;
    hist[2 * tid]     = s + excl;           // absolute start
    hist[2 * tid + 1] = s + excl + a0;
    __syncthreads();
    // write nodeStart for this bucket's nodes
    int nbase = b * CW;
    for (int l = tid; l < CW; l += 1024) {
        int n = nbase + l;
        if (n < N) nodeStart[n] = hist[l];
    }
    if (b == NBC - 1 && tid == 0) nodeStart[N] = E;
    __syncthreads();
    // cursor scatter into node order; drop lrow (position encodes it)
    for (int i = s + tid; i < e; i += 1024) {
        uint2 rc = rec[i];
        int slot = atomicAdd(&hist[rc.y], 1);
        rec2[slot] = rc.x;                  // col | T<<19 | nt<<22
    }
}

// ---- consume: 512thr/128 nodes; 4-way replica record split + LDS combine --
__global__ __launch_bounds__(512) void consume_kernel(
    const int* __restrict__ nodeStart, const unsigned* __restrict__ rec2,
    const uint2* __restrict__ xh, const float* __restrict__ Wc,
    const int* __restrict__ batch, const float* __restrict__ inj,
    float* __restrict__ out, int N)
{
    __shared__ int seg[WSZ + 1];
    __shared__ unsigned sbuf[3 * CAP];      // smeta | sx01 | sx23, then red
    unsigned* smeta = sbuf;
    unsigned* sx01  = sbuf + CAP;
    unsigned* sx23  = sbuf + 2 * CAP;
    int tid = threadIdx.x;
    int f = blockIdx.x;
    int node0 = f << WSH;
    int nodes = N - node0; if (nodes > WSZ) nodes = WSZ;

    for (int i = tid; i <= nodes; i += 512) seg[i] = nodeStart[node0 + i];
    __syncthreads();
    int s = seg[0], e = seg[nodes];

    int nl = tid & (WSZ - 1);
    int rep = tid >> 7;                    // 0..3, wave-uniform
    int myS = (nl < nodes) ? seg[nl] : e;
    int myE = (nl < nodes) ? seg[nl + 1] : e;

    float acc[20] = {};                    // [T][0..3] x-sums
    int cnt0[5] = {}, cnt1[5] = {};        // 8-bit packed nt counts
    for (int base = s; base < e; base += CAP) {
        int w = e - base; if (w > CAP) w = CAP;
        __syncthreads();                   // protect stage reuse
        for (int i = tid; i < w; i += 512) {
            unsigned u = rec2[base + i];
            smeta[i] = u;
            uint2 p = xh[u & 0x7FFFFu];
            sx01[i] = p.x;
            sx23[i] = p.y;
        }
        __syncthreads();
        // replica rep handles j = myS + rep + 4k
        int jstart = myS + rep;
        if (jstart < base)
            jstart += ((base - jstart + 3) >> 2) << 2;
        int jend = myE < base + w ? myE : base + w;
        for (int j = jstart; j < jend; j += 4) {
            int k = j - base;
            unsigned u = smeta[k];
            int T  = (int)((u >> 19) & 7u);
            int nt = (int)((u >> 22) & 7u);
            float2 x01 = unpack2(sx01[k]);
            float2 x23 = unpack2(sx23[k]);
            int lob = (nt < 4) ? (1 << (nt * 8)) : 0;
            int hib = (nt >= 4) ? (1 << ((nt - 4) * 8)) : 0;
#pragma unroll
            for (int tt = 0; tt < 5; ++tt) {
                bool m = (T == tt);
                acc[tt * 4 + 0] += m ? x01.x : 0.f;
                acc[tt * 4 + 1] += m ? x01.y : 0.f;
                acc[tt * 4 + 2] += m ? x23.x : 0.f;
                acc[tt * 4 + 3] += m ? x23.y : 0.f;
                cnt0[tt] += m ? lob : 0;
                cnt1[tt] += m ? hib : 0;
            }
        }
    }

    // combine the 4 replica partials: 3 passes of 10 values via sbuf reuse
    // slot stride 43 (odd, coprime 32) -> conflict-free
    {
        float* redf = (float*)sbuf;
        int*   redi = (int*)sbuf;
        int wslot = nl * 43 + rep * 10;
        int rbase = nl * 43;
#pragma unroll
        for (int p = 0; p < 3; ++p) {
            __syncthreads();
            if (p < 2) {
#pragma unroll
                for (int i = 0; i < 10; ++i) redf[wslot + i] = acc[p * 10 + i];
            } else {
#pragma unroll
                for (int i = 0; i < 5; ++i) {
                    redi[wslot + i]     = cnt0[i];
                    redi[wslot + 5 + i] = cnt1[i];
                }
            }
            __syncthreads();
            if (p < 2) {
#pragma unroll
                for (int i = 0; i < 10; ++i)
                    acc[p * 10 + i] = redf[rbase + i] + redf[rbase + 10 + i] +
                                      redf[rbase + 20 + i] + redf[rbase + 30 + i];
            } else {
#pragma unroll
                for (int i = 0; i < 5; ++i) {
                    cnt0[i] = redi[rbase + i] + redi[rbase + 10 + i] +
                              redi[rbase + 20 + i] + redi[rbase + 30 + i];
                    cnt1[i] = redi[rbase + 5 + i] + redi[rbase + 15 + i] +
                              redi[rbase + 25 + i] + redi[rbase + 35 + i];
                }
            }
        }
    }

    if (nl < nodes) {
        int hf = __builtin_amdgcn_readfirstlane(rep);        // 0..3
        const float4* wq = (const float4*)Wc;
        float4 o0 = {0.f, 0.f, 0.f, 0.f}, o1 = o0;
#pragma unroll
        for (int f2 = 0; f2 < 55; ++f2) {
            const int tt = f2 / 11, j = f2 % 11;
            float a;
            if (j < 4) a = acc[tt * 4 + j];
            else {
                const int kk = j - 4;
                a = (kk < 4) ? (float)((cnt0[tt] >> (kk * 8)) & 255)
                             : (float)((cnt1[tt] >> ((kk - 4) * 8)) & 255);
            }
            float4 w0 = wq[f2 * 8 + hf * 2];
            float4 w1 = wq[f2 * 8 + hf * 2 + 1];
            o0.x += a * w0.x; o0.y += a * w0.y; o0.z += a * w0.z; o0.w += a * w0.w;
            o1.x += a * w1.x; o1.y += a * w1.y; o1.z += a * w1.z; o1.w += a * w1.w;
        }
        int n = node0 + nl;
        int bb = batch[n];
        const float4* iv = ((const float4*)inj) + bb * 8 + hf * 2;
        float4 i0 = iv[0], i1 = iv[1];
        float4 r0, r1;
        r0.x = i0.x + 0.2f * o0.x; r0.y = i0.y + 0.2f * o0.y;
        r0.z = i0.z + 0.2f * o0.z; r0.w = i0.w + 0.2f * o0.w;
        r1.x = i1.x + 0.2f * o1.x; r1.y = i1.y + 0.2f * o1.y;
        r1.z = i1.z + 0.2f * o1.z; r1.w = i1.w + 0.2f * o1.w;
        float4* op = ((float4*)out) + (size_t)n * 8 + hf * 2;
        op[0] = r0; op[1] = r1;
    }
}

// ---- fallback: fused temb + init + direct atomic scatter ------------------
__global__ __launch_bounds__(256) void temb_fused_kernel(
    const float* __restrict__ t,
    const float* __restrict__ W1, const float* __restrict__ b1,
    const float* __restrict__ W2, const float* __restrict__ b2,
    const float* __restrict__ Wt, float* __restrict__ inj)
{
    int b = blockIdx.x;
    int tid = threadIdx.x;
    __shared__ float emb[128];
    __shared__ float s1[512];
    __shared__ float s2[512];
    __shared__ float red[256];
    float tv = t[b];
    if (tid < 128) {
        const float kStep = 9.210340371976184f / 63.0f;
        int k = tid & 63;
        float ang = tv * expf(-(float)k * kStep);
        emb[tid] = (tid < 64) ? sinf(ang) : cosf(ang);
    }
    __syncthreads();
    {
        float a0 = 0.f, a1 = 0.f;
        for (int k = 0; k < 128; ++k) {
            float e = emb[k];
            a0 += e * W1[k * 512 + tid];
            a1 += e * W1[k * 512 + tid + 256];
        }
        float v0 = a0 + b1[tid], v1 = a1 + b1[tid + 256];
        s1[tid]       = v0 / (1.0f + expf(-v0));
        s1[tid + 256] = v1 / (1.0f + expf(-v1));
    }
    __syncthreads();
    {
        float a0 = 0.f, a1 = 0.f;
        for (int k = 0; k < 512; ++k) {
            float e = s1[k];
            a0 += e * W2[k * 512 + tid];
            a1 += e * W2[k * 512 + tid + 256];
        }
        float v0 = a0 + b2[tid], v1 = a1 + b2[tid + 256];
        s2[tid]       = v0 / (1.0f + expf(-v0));
        s2[tid + 256] = v1 / (1.0f + expf(-v1));
    }
    __syncthreads();
    {
        int c = tid & 31, seg = tid >> 5;
        float acc = 0.f;
        int k0 = seg * 64;
        for (int k = k0; k < k0 + 64; ++k)
            acc += s2[k] * Wt[k * 32 + c];
        red[tid] = acc;
        __syncthreads();
        if (tid < 32) {
            float s = 0.f;
#pragma unroll
            for (int g = 0; g < 8; ++g) s += red[g * 32 + tid];
            inj[b * 32 + tid] = s;
        }
    }
}

__global__ __launch_bounds__(256) void init_kernel(
    const int* __restrict__ batch_id, const float* __restrict__ inj,
    float4* __restrict__ out, int N)
{
    int gid = blockIdx.x * 256 + threadIdx.x;
    if (gid >= N * 8) return;
    int n = gid >> 3, q = gid & 7;
    int b = batch_id[n];
    out[gid] = ((const float4*)inj)[b * 8 + q];
}

__global__ __launch_bounds__(256) void edge_direct_kernel(
    const int* __restrict__ ei, const int* __restrict__ etype,
    const int* __restrict__ ntype, const float* __restrict__ x,
    const float* __restrict__ Wc, float* __restrict__ out, int E)
{
    __shared__ float Ws[55 * 32];
    for (int i = threadIdx.x; i < 55 * 32; i += 256) Ws[i] = Wc[i];
    __syncthreads();
    unsigned total = (unsigned)E * 32u;
    unsigned stride = gridDim.x * 256u;
    for (unsigned idx = blockIdx.x * 256u + threadIdx.x; idx < total;
         idx += stride) {
        int e = (int)(idx >> 5);
        int c = (int)(idx & 31);
        int row = ei[e];
        int col = ei[E + e];
        int T = etype[e];
        int nt = ntype[col];
        float4 xv = ((const float4*)x)[col];
        const float* wb = Ws + T * 352;
        float y = xv.x * wb[c] + xv.y * wb[32 + c] + xv.z * wb[64 + c] +
                  xv.w * wb[96 + c] + wb[(4 + nt) * 32 + c];
        atomicAdd(out + (size_t)row * 32 + c, y * 0.2f);
    }
}

extern "C" void kernel_launch(void* const* d_in, const int* in_sizes, int n_in,
                              void* d_out, int out_size, void* d_ws, size_t ws_size,
                              hipStream_t stream) {
    const float* x     = (const float*)d_in[0];   // [N,4]
    const float* t     = (const float*)d_in[1];   // [8]
    const int*   ei    = (const int*)d_in[2];     // [2,E]
    const int*   etype = (const int*)d_in[3];     // [E]
    const int*   ntype = (const int*)d_in[4];     // [N]
    const int*   batch = (const int*)d_in[5];     // [N]
    const float* Wc    = (const float*)d_in[6];   // [55,32]
    const float* W1    = (const float*)d_in[7];   // [128,512]
    const float* b1    = (const float*)d_in[8];   // [512]
    const float* W2    = (const float*)d_in[9];   // [512,512]
    const float* b2    = (const float*)d_in[10];  // [512]
    const float* Wt    = (const float*)d_in[11];  // [512,32]
    float* out = (float*)d_out;

    int E = in_sizes[3];
    int N = in_sizes[4];

    int NBC = (N + CW - 1) >> CWSH;               // coarse buckets
    int NFr = (N + WSZ - 1) >> WSH;               // consume blocks
    int NCH = (E + CH - 1) / CH;
    int NCHP = 1, LOGC = 0;
    while (NCHP < NCH) { NCHP <<= 1; ++LOGC; }
    size_t M = (size_t)NBC << LOGC;
    int nblkA = (int)((M + 4095) / 4096);

    // ws layout (4-byte units)
    float* ws     = (float*)d_ws;
    float* h1acc  = ws;                           // 4096
    float* h2acc  = ws + 4096;                    // 4096
    float* inj    = ws + 8192;                    // 256
    uint2* xh     = (uint2*)(ws + 8448);          // 2N words
    int*   counts = (int*)(ws + 8448 + 2 * (size_t)N);  // M
    int*   base   = counts + M;                   // M
    int*   bsums  = base + M;                     // 1024
    int*   bstart = bsums + 1024;                 // NBC+1
    int*   nodeSt = bstart + NBC + 1;             // N+1
    size_t recOff = 8448 + 2 * (size_t)N + 2 * M + 1024 + (NBC + 1) +
                    ((size_t)N + 1);
    recOff = (recOff + 1) & ~(size_t)1;           // 8B align
    uint2*    rec  = (uint2*)(ws + recOff);       // 2E words
    unsigned* rec2 = (unsigned*)(ws + recOff + 2 * (size_t)E);  // E words

    size_t needBytes = (recOff + 3 * (size_t)E) * 4;
    bool okay = (NBC <= NBCMAX) && (nblkA <= 1024) && (ws_size >= needBytes) &&
                (N <= NBCMAX * CW) && ((E & 3) == 0) && (M < (size_t)1 << 30);

    if (okay) {
        histW_kernel<<<NCHP + 8, 256, 0, stream>>>(
            ei, counts, x, xh, t, W1, h1acc, h2acc, inj, E, N, NBC, NCHP);
        scanA_kernel<<<nblkA + 64, 256, 0, stream>>>(
            counts, bsums, h1acc, b1, W2, h2acc, (int)M, NBC, LOGC, nblkA);
        scanB_kernel<<<1, 1024, 0, stream>>>(bsums, bstart, nblkA, NBC, E);
        scanC_kernel<<<nblkA + 8, 256, 0, stream>>>(
            counts, bsums, base, bstart, h2acc, b2, Wt, inj,
            (int)M, NBC, LOGC, nblkA);
        scatter_kernel<<<NCH, 512, 0, stream>>>(
            ei, etype, ntype, base, rec, E, NBC, LOGC);
        repack_kernel<<<NBC, 1024, 0, stream>>>(
            bstart, rec, rec2, nodeSt, NBC, N, E);
        consume_kernel<<<NFr, 512, 0, stream>>>(
            nodeSt, rec2, xh, Wc, batch, inj, out, N);
    } else {
        temb_fused_kernel<<<8, 256, 0, stream>>>(t, W1, b1, W2, b2, Wt, inj);
        init_kernel<<<(N * 8 + 255) / 256, 256, 0, stream>>>(
            batch, inj, (float4*)out, N);
        edge_direct_kernel<<<16384, 256, 0, stream>>>(
            ei, etype, ntype, x, Wc, out, E);
    }
}